// Round 13
// baseline (44.961 us; speedup 1.0000x reference)
//
#include <hip/hip_runtime.h>
#include <math.h>

// PolyaTree R13 (= R12 with constexpr DPP ctrl): lane-owns-(point,dim).
// 16M work items, one depth-8 descent per lane. Per wave-iteration (64
// chains = 4 points): 8 DS instrs; VALU ~11 instrs/point (was ~50 in R3).
// Cross-dim sum via DPP row_ror (VALU pipe; __shfl would burn DS instrs).
// LDS stride 129 spreads dim-subtables across banks (128 aliases to bank 0).
// Prologue: R11's shuffle tree build (validated bit-exact, absmax 0.03125).
// Eval decisions byte-identical to R3.

constexpr int DIMS    = 16;
constexpr int NODES   = 255;
constexpr int STRIDE  = 129;              // +1 pad: banks spread across dims
constexpr int LDSW    = DIMS * STRIDE;    // 2064 words per table

template <int N>
__device__ __forceinline__ float row_ror_addf(float f) {
    // f + rotate-within-16-lane-row(f, N); DPP ctrl row_ror:N = 0x120+N
    int r = __builtin_amdgcn_update_dpp(0, __float_as_int(f), 0x120 + N, 0xF, 0xF, true);
    return f + __int_as_float(r);
}

__global__ __launch_bounds__(256) void polya_fused(
    const float* __restrict__ x,        // (n,16) row-major = 16M floats
    const float* __restrict__ samples,  // (16,255)
    float* __restrict__ out,
    int n)
{
#pragma clang fp contract(off)
    __shared__ float s_split[LDSW];     // internal splits [d*129 + j], j<127
    __shared__ float s_value[LDSW];     // leaf values [d*129 + (j-127)]

    // ---- prologue: shuffle tree build (R11-validated); wave w: dims 4w.. ----
    {
        const int lane = threadIdx.x & 63;
        const int wid  = threadIdx.x >> 6;
#pragma unroll
        for (int dd = 0; dd < 4; ++dd) {
            const int d = wid * 4 + dd;
            const float* s = samples + d * NODES;
            float lo = 0.0f, hi = 1.0f, ac = 0.0f;
            float sp = 0.0f, rhi = 0.0f, ac2 = 0.0f;
#pragma unroll
            for (int l = 0; l <= 6; ++l) {
                if (l > 0) {
                    const int pl = lane >> 1;
                    const float plo = __shfl(lo,  pl);
                    const float psp = __shfl(sp,  pl);
                    const float prh = __shfl(rhi, pl);
                    const float pac = __shfl(ac2, pl);
                    lo = (lane & 1) ? psp : plo;
                    hi = (lane & 1) ? prh : psp;
                    ac = pac;
                }
                if (lane < (1 << l)) {
                    const int i = (1 << l) - 1 + lane;     // node id, level l
                    const float b = s[i];
                    const float len = hi - lo;
                    sp  = lo + b * len;                    // EXACT mirror (no fma)
                    rhi = sp + (1.0f - b) * len;
                    ac2 = ac + logf(b);                    // left-assoc chain
                    s_split[d * STRIDE + i] = sp;
                    if (l == 6) {                          // children = leaves
                        const int jl = 2 * i + 1;          // 127 + 2*lane
                        const float vl = ac2 + logf(s[jl])     - logf(sp  - lo);
                        const float vr = ac2 + logf(s[jl + 1]) - logf(rhi - sp);
                        s_value[d * STRIDE + 2 * lane]     = vl;
                        s_value[d * STRIDE + 2 * lane + 1] = vr;
                    }
                }
            }
        }
    }
    __syncthreads();

    // ---- eval: one chain per lane; 16-lane rows = one point ----
    const unsigned total   = (unsigned)n * 16u;
    const unsigned gstride = gridDim.x * 256u;          // multiple of 16
    const unsigned gid     = blockIdx.x * 256u + threadIdx.x;
    const int dbase = (int)(gid & 15u) * STRIDE;        // dim fixed per lane
    const bool writer = (gid & 15u) == 0u;

    for (unsigned w = gid; w < total; w += gstride) {
        const float xv = x[w];
        int q = 0;
#pragma unroll
        for (int l = 0; l < 7; ++l) {
            const float sp = s_split[dbase + q];
            q = 2 * q + 1 + (int)(xv > sp);             // x<=split -> left
        }
        float f = s_value[dbase + (q - 127)];
        // sum over the 16 lanes of this point (VALU-only DPP rotate-adds)
        f = row_ror_addf<1>(f);
        f = row_ror_addf<2>(f);
        f = row_ror_addf<4>(f);
        f = row_ror_addf<8>(f);
        if (writer) out[w >> 4] = f * 0.0625f;          // mean over 16 dims
    }
}

extern "C" void kernel_launch(void* const* d_in, const int* in_sizes, int n_in,
                              void* d_out, int out_size, void* d_ws, size_t ws_size,
                              hipStream_t stream) {
    const float* x       = (const float*)d_in[0];   // (n,16) f32
    const float* samples = (const float*)d_in[1];   // (16,255) f32
    float* out = (float*)d_out;
    const int n = in_sizes[0] / DIMS;

    // 2048 blocks x 16.1 KB LDS x tiny VGPR -> 8 blocks/CU resident,
    // 32 waves/CU; prologue paid once per block, in parallel.
    polya_fused<<<2048, 256, 0, stream>>>(x, samples, out, n);
}

// Round 14
// 34.773 us; speedup vs baseline: 1.2930x; 1.2930x over previous
//
#include <hip/hip_runtime.h>
#include <math.h>

// PolyaTree R14: lane-owns-point (R3/R10 conflict-free flat layout) +
// DS-pipe feeding: 2 points/thread with dual interleaved descent chains
// (2 independent ds_reads in flight per level) + 16 KB prologue (shuffle
// tree build, bit-exact since R11) so ~7.6 blocks/CU reside (R10's 40 KB
// frontier capped it at 4). Theory: R10's 32.3us = 20us DS floor / 62%
// utilization; more chains/CU -> DS ~saturated -> ~24-27us.

constexpr int DIMS  = 16;
constexpr int NODES = 255;

__global__ __launch_bounds__(256) __attribute__((amdgpu_waves_per_eu(6)))
void polya_fused(
    const float* __restrict__ x,        // (n,16)
    const float* __restrict__ samples,  // (16,255)
    float* __restrict__ out,
    int n)
{
#pragma clang fp contract(off)
    __shared__ float s_split[DIMS * 128];   // 8 KB: splits [d*128 + j], j<127
    __shared__ float s_value[DIMS * 128];   // 8 KB: leaf values [d*128+(j-127)]

    // ---- prologue: shuffle tree build (R11-validated, bit-exact) ----
    {
        const int lane = threadIdx.x & 63;
        const int wid  = threadIdx.x >> 6;
#pragma unroll
        for (int dd = 0; dd < 4; ++dd) {
            const int d = wid * 4 + dd;
            const float* s = samples + d * NODES;
            float lo = 0.0f, hi = 1.0f, ac = 0.0f;
            float sp = 0.0f, rhi = 0.0f, ac2 = 0.0f;
#pragma unroll
            for (int l = 0; l <= 6; ++l) {
                if (l > 0) {
                    const int pl = lane >> 1;
                    const float plo = __shfl(lo,  pl);
                    const float psp = __shfl(sp,  pl);
                    const float prh = __shfl(rhi, pl);
                    const float pac = __shfl(ac2, pl);
                    lo = (lane & 1) ? psp : plo;
                    hi = (lane & 1) ? prh : psp;
                    ac = pac;
                }
                if (lane < (1 << l)) {
                    const int i = (1 << l) - 1 + lane;     // node id, level l
                    const float b = s[i];
                    const float len = hi - lo;
                    sp  = lo + b * len;                    // EXACT mirror (no fma)
                    rhi = sp + (1.0f - b) * len;
                    ac2 = ac + logf(b);                    // left-assoc chain
                    s_split[(d << 7) + i] = sp;
                    if (l == 6) {                          // children = leaves
                        const int jl = 2 * i + 1;          // 127 + 2*lane
                        const float vl = ac2 + logf(s[jl])     - logf(sp  - lo);
                        const float vr = ac2 + logf(s[jl + 1]) - logf(rhi - sp);
                        s_value[(d << 7) + 2 * lane]     = vl;
                        s_value[(d << 7) + 2 * lane + 1] = vr;
                    }
                }
            }
        }
    }
    __syncthreads();

    // ---- eval: 2 points/thread, dual interleaved chains ----
    const int p0 = blockIdx.x * 512 + threadIdx.x;
    const int p1 = p0 + 256;
    const int lp0 = (p0 < n) ? p0 : 0;          // clamp loads, guard stores
    const int lp1 = (p1 < n) ? p1 : 0;

    const float4* xr0 = reinterpret_cast<const float4*>(x + (size_t)lp0 * DIMS);
    const float4* xr1 = reinterpret_cast<const float4*>(x + (size_t)lp1 * DIMS);
    float4 a0 = xr0[0], b0v = xr0[1], c0 = xr0[2], e0 = xr0[3];
    float4 a1 = xr1[0], b1v = xr1[1], c1 = xr1[2], e1 = xr1[3];
    float xa[DIMS] = {a0.x, a0.y, a0.z, a0.w,  b0v.x, b0v.y, b0v.z, b0v.w,
                      c0.x, c0.y, c0.z, c0.w,  e0.x,  e0.y,  e0.z,  e0.w};
    float xb[DIMS] = {a1.x, a1.y, a1.z, a1.w,  b1v.x, b1v.y, b1v.z, b1v.w,
                      c1.x, c1.y, c1.z, c1.w,  e1.x,  e1.y,  e1.z,  e1.w};

    float acc0 = 0.0f, acc1 = 0.0f;
#pragma unroll
    for (int d = 0; d < DIMS; ++d) {
        const float xv0 = xa[d], xv1 = xb[d];
        int q0 = 0, q1 = 0;
#pragma unroll
        for (int l = 0; l < 7; ++l) {
            const float sp0 = s_split[(d << 7) + q0];   // 2 independent reads
            const float sp1 = s_split[(d << 7) + q1];
            q0 = 2 * q0 + 1 + (int)(xv0 > sp0);         // x<=split -> left
            q1 = 2 * q1 + 1 + (int)(xv1 > sp1);
        }
        acc0 += s_value[(d << 7) + (q0 - 127)];
        acc1 += s_value[(d << 7) + (q1 - 127)];
    }
    if (p0 < n) out[p0] = acc0 * 0.0625f;   // mean over 16 dims (exact /16)
    if (p1 < n) out[p1] = acc1 * 0.0625f;
}

extern "C" void kernel_launch(void* const* d_in, const int* in_sizes, int n_in,
                              void* d_out, int out_size, void* d_ws, size_t ws_size,
                              hipStream_t stream) {
    const float* x       = (const float*)d_in[0];   // (n,16) f32
    const float* samples = (const float*)d_in[1];   // (16,255) f32
    float* out = (float*)d_out;
    const int n = in_sizes[0] / DIMS;

    const int blocks = (n + 511) / 512;             // 1954: 2 points/thread
    polya_fused<<<blocks, 256, 0, stream>>>(x, samples, out, n);
}